// Round 8
// baseline (127.406 us; speedup 1.0000x reference)
//
#include <hip/hip_runtime.h>
#include <hip/hip_bf16.h>

#define N_NODES 100000
#define N_EDGES 1600000
#define D_IN    128
#define D_HID   16
#define D_OUT   32

#define BSHIFT 6
#define BNODES 64                  // nodes per bucket
#define NB 1563                    // ceil(100000/64)
#define NBPAD2 2048                // scan padding (256 threads x 8)
#define SCHUNK 4096                // edges per block chunk
#define SBLOCKS 391                // ceil(1600000/4096)
#define SORTCAP 2048               // per-bucket edge cap (mean 1024, sd 32)

// bf16x2 helpers -------------------------------------------------------------
__device__ inline float bf_lo(unsigned dw) { return __uint_as_float(dw << 16); }
__device__ inline float bf_hi(unsigned dw) { return __uint_as_float(dw & 0xffff0000u); }
__device__ inline unsigned bf_pack(float f0, float f1) {
    union { __hip_bfloat16 h[2]; unsigned u; } pu;
    pu.h[0] = __float2bfloat16(f0);
    pu.h[1] = __float2bfloat16(f1);
    return pu.u;
}

// ---------------------------------------------------------------------------
// K1: mm1 (Y = feat @ W1 -> packed bf16) + per-block dst-bucket histogram.
// Block blk: nodes [blk*256, +256), edges [blk*4096, +4096).
// blockhist[blk][b] written coalesced; no global atomics, no zeroing kernel.
// ---------------------------------------------------------------------------
__global__ __launch_bounds__(256) void k_mm1h(const float* __restrict__ feat,
                                              const float* __restrict__ W1,
                                              const int* __restrict__ dst,
                                              unsigned* __restrict__ Yu,
                                              int* __restrict__ blockhist) {
    __shared__ float sW[D_IN * D_HID];  // 8 KB
    __shared__ int h[NB];               // 6.25 KB
    int tid = threadIdx.x, blk = blockIdx.x;
    for (int i = tid; i < D_IN * D_HID; i += 256) sW[i] = W1[i];
    for (int i = tid; i < NB; i += 256) h[i] = 0;
    __syncthreads();

    // histogram of this block's edge chunk (LDS int atomics)
    int ebase = blk * SCHUNK;
#pragma unroll
    for (int k = 0; k < 16; ++k) {
        int e = ebase + k * 256 + tid;
        if (e < N_EDGES) atomicAdd(&h[dst[e] >> BSHIFT], 1);
    }

    // mm1 for one node (independent of h)
    int n = blk * 256 + tid;
    if (n < N_NODES) {
        const float4* f4 = (const float4*)(feat + (size_t)n * D_IN);
        const float4* sW4 = (const float4*)sW;
        float4 acc[4];
#pragma unroll
        for (int q = 0; q < 4; ++q) acc[q] = make_float4(0.f, 0.f, 0.f, 0.f);
#pragma unroll 8
        for (int kq = 0; kq < 32; ++kq) {
            float4 f = f4[kq];
            int k0 = kq * 4;
#pragma unroll
            for (int jq = 0; jq < 4; ++jq) {
                float4 w0 = sW4[(k0 + 0) * 4 + jq];
                float4 w1 = sW4[(k0 + 1) * 4 + jq];
                float4 w2 = sW4[(k0 + 2) * 4 + jq];
                float4 w3 = sW4[(k0 + 3) * 4 + jq];
                acc[jq].x += f.x * w0.x + f.y * w1.x + f.z * w2.x + f.w * w3.x;
                acc[jq].y += f.x * w0.y + f.y * w1.y + f.z * w2.y + f.w * w3.y;
                acc[jq].z += f.x * w0.z + f.y * w1.z + f.z * w2.z + f.w * w3.z;
                acc[jq].w += f.x * w0.w + f.y * w1.w + f.z * w2.w + f.w * w3.w;
            }
        }
        uint4 o0, o1;
        o0.x = bf_pack(acc[0].x, acc[0].y);
        o0.y = bf_pack(acc[0].z, acc[0].w);
        o0.z = bf_pack(acc[1].x, acc[1].y);
        o0.w = bf_pack(acc[1].z, acc[1].w);
        o1.x = bf_pack(acc[2].x, acc[2].y);
        o1.y = bf_pack(acc[2].z, acc[2].w);
        o1.z = bf_pack(acc[3].x, acc[3].y);
        o1.w = bf_pack(acc[3].z, acc[3].w);
        uint4* y = (uint4*)(Yu + (size_t)n * 8);
        y[0] = o0;
        y[1] = o1;
    }
    __syncthreads();
    size_t rowbase = (size_t)blk * NB;
    for (int i = tid; i < NB; i += 256) blockhist[rowbase + i] = h[i];
}

// ---------------------------------------------------------------------------
// K2: per-bucket running prefix over blocks. rowpre[blk][b] = sum of
// blockhist[blk'<blk][b]; colsum[b] = bucket total. Coalesced across threads.
// ---------------------------------------------------------------------------
__global__ __launch_bounds__(256) void k_rowpre(const int* __restrict__ blockhist,
                                                int* __restrict__ rowpre,
                                                int* __restrict__ colsum) {
    int b = blockIdx.x * 256 + threadIdx.x;
    if (b >= NB) return;
    int run = 0;
    for (int blk = 0; blk < SBLOCKS; ++blk) {
        size_t idx = (size_t)blk * NB + b;
        int v = blockhist[idx];
        rowpre[idx] = run;
        run += v;
    }
    colsum[b] = run;
}

// ---------------------------------------------------------------------------
// K3: exclusive scan of colsum -> offsets[NB+1].
// ---------------------------------------------------------------------------
__global__ __launch_bounds__(256) void k_scan(const int* __restrict__ colsum,
                                              int* __restrict__ offsets) {
    __shared__ int t[256];
    int tid = threadIdx.x;
    int i0 = tid * 8;
    int v[8];
    int lsum = 0;
#pragma unroll
    for (int m = 0; m < 8; ++m) {
        int idx = i0 + m;
        v[m] = (idx < NB) ? colsum[idx] : 0;
        lsum += v[m];
    }
    t[tid] = lsum;
    __syncthreads();
#pragma unroll
    for (int off = 1; off < 256; off <<= 1) {
        int x = (tid >= off) ? t[tid - off] : 0;
        __syncthreads();
        t[tid] += x;
        __syncthreads();
    }
    int excl = t[tid] - lsum;
#pragma unroll
    for (int m = 0; m < 8; ++m) {
        int idx = i0 + m;
        if (idx < NB) offsets[idx] = excl;
        excl += v[m];
    }
    if (tid == 0) offsets[NB] = N_EDGES;
}

// ---------------------------------------------------------------------------
// K4: deterministic bucket-grouping sort. Reads own blockhist row (no local
// hist rebuild), scans it for local bases, places edges into sorted LDS, and
// streams out at gb[b] = offsets[b] + rowpre[blk][b] (no global atomics).
// ---------------------------------------------------------------------------
__global__ __launch_bounds__(256) void k_sortplace(const int* __restrict__ src,
                                                   const int* __restrict__ dst,
                                                   const int* __restrict__ offsets,
                                                   const int* __restrict__ blockhist,
                                                   const int* __restrict__ rowpre,
                                                   unsigned* __restrict__ pairs) {
    __shared__ int lb[NBPAD2];            // 8 KB
    __shared__ int cur[NBPAD2];           // 8 KB
    __shared__ int gb[NB];                // 6.25 KB
    __shared__ int tscan[256];            // 1 KB
    __shared__ unsigned sorted[SCHUNK];   // 16 KB
    __shared__ unsigned short bId[SCHUNK];// 8 KB   (~47.4 KB total -> 3 blk/CU)
    int tid = threadIdx.x, blk = blockIdx.x;
    int ebase = blk * SCHUNK;
    int nval = N_EDGES - ebase;
    if (nval > SCHUNK) nval = SCHUNK;
    size_t rowbase = (size_t)blk * NB;

    // issue edge loads early
    int varr[16], barr[16];
#pragma unroll
    for (int k = 0; k < 16; ++k) {
        int e = ebase + k * 256 + tid;
        if (e < N_EDGES) {
            int s = src[e], d = dst[e];
            varr[k] = (s << BSHIFT) | (d & (BNODES - 1));
            barr[k] = d >> BSHIFT;
        } else {
            barr[k] = -1;
        }
    }

    // local bases from own blockhist row
    int i0 = tid * 8;
    int hv[8];
    int lsum = 0;
#pragma unroll
    for (int m = 0; m < 8; ++m) {
        int idx = i0 + m;
        hv[m] = (idx < NB) ? blockhist[rowbase + idx] : 0;
        lsum += hv[m];
    }
    tscan[tid] = lsum;
    __syncthreads();
#pragma unroll
    for (int off = 1; off < 256; off <<= 1) {
        int x = (tid >= off) ? tscan[tid - off] : 0;
        __syncthreads();
        tscan[tid] += x;
        __syncthreads();
    }
    int excl = tscan[tid] - lsum;
#pragma unroll
    for (int m = 0; m < 8; ++m) {
        lb[i0 + m] = excl;
        cur[i0 + m] = excl;
        excl += hv[m];
    }
    for (int i = tid; i < NB; i += 256)
        gb[i] = offsets[i] + rowpre[rowbase + i];
    __syncthreads();

    // place into sorted LDS
#pragma unroll
    for (int k = 0; k < 16; ++k) {
        int b = barr[k];
        if (b >= 0) {
            int p = atomicAdd(&cur[b], 1);
            sorted[p] = (unsigned)varr[k];
            bId[p] = (unsigned short)b;
        }
    }
    __syncthreads();

    // deterministic writeout: consecutive i -> consecutive addrs within runs
    for (int i = tid; i < nval; i += 256) {
        int b = bId[i];
        pairs[gb[b] + (i - lb[b])] = sorted[i];
    }
}

// ---------------------------------------------------------------------------
// K5: fused per-bucket node sort + layer-1 aggregation. Sorts the bucket's
// edges by dst node in LDS, writes node_off + csr (for agg2), then gathers Y
// straight from the LDS-sorted src list with register accumulation.
// Fused bias+ReLU -> packed bf16 H1.
// ---------------------------------------------------------------------------
__global__ __launch_bounds__(256) void k_sortagg1(const int* __restrict__ offsets,
                                                  unsigned* __restrict__ pairs,
                                                  const unsigned* __restrict__ Yu,
                                                  const float* __restrict__ bias1,
                                                  unsigned* __restrict__ H1u,
                                                  int* __restrict__ node_off) {
    __shared__ unsigned buf[SORTCAP];   // 8 KB
    __shared__ unsigned sbuf[SORTCAP];  // 8 KB
    __shared__ int hist[BNODES];
    __shared__ int lbase[BNODES];
    __shared__ int cur[BNODES];
    __shared__ float sB[D_HID];
    int tid = threadIdx.x, b = blockIdx.x;
    int beg = offsets[b], end = offsets[b + 1];
    int cnt = end - beg;
    if (cnt > SORTCAP) cnt = SORTCAP;
    if (tid < BNODES) hist[tid] = 0;
    if (tid < D_HID) sB[tid] = bias1[tid];
    __syncthreads();

    for (int i = tid; i < cnt; i += 256) {
        unsigned p = pairs[beg + i];
        buf[i] = p;
        atomicAdd(&hist[p & (BNODES - 1)], 1);
    }
    __syncthreads();

    if (tid == 0) {
        int run = 0;
#pragma unroll
        for (int l = 0; l < BNODES; ++l) {
            lbase[l] = run;
            cur[l] = run;
            run += hist[l];
        }
    }
    __syncthreads();

    if (tid < BNODES) node_off[b * BNODES + tid] = beg + lbase[tid];
    if (b == 0 && tid == 0) node_off[NB * BNODES] = N_EDGES;

    for (int i = tid; i < cnt; i += 256) {
        unsigned p = buf[i];
        int pos = atomicAdd(&cur[p & (BNODES - 1)], 1);
        unsigned sid = p >> BSHIFT;
        sbuf[pos] = sid;
        pairs[beg + pos] = sid;     // global csr for agg2
    }
    __syncthreads();

    // gather-accumulate: 8 lanes per node, 2 nodes per 8-lane group
    int c = tid & 7;
    int grp = tid >> 3;
#pragma unroll
    for (int rep = 0; rep < 2; ++rep) {
        int ln = grp * 2 + rep;
        int n = b * BNODES + ln;
        if (n >= N_NODES) continue;
        int s = lbase[ln], e = cur[ln];   // cur = lbase + count after placement
        float a0 = 0.f, a1 = 0.f, b0 = 0.f, b1v = 0.f;
        float c0 = 0.f, c1 = 0.f, d0f = 0.f, d1f = 0.f;
        int i = s;
        for (; i + 3 < e; i += 4) {
            unsigned w0 = Yu[(size_t)sbuf[i]     * 8 + c];
            unsigned w1 = Yu[(size_t)sbuf[i + 1] * 8 + c];
            unsigned w2 = Yu[(size_t)sbuf[i + 2] * 8 + c];
            unsigned w3 = Yu[(size_t)sbuf[i + 3] * 8 + c];
            a0 += bf_lo(w0); a1 += bf_hi(w0);
            b0 += bf_lo(w1); b1v += bf_hi(w1);
            c0 += bf_lo(w2); c1 += bf_hi(w2);
            d0f += bf_lo(w3); d1f += bf_hi(w3);
        }
        for (; i < e; ++i) {
            unsigned w = Yu[(size_t)sbuf[i] * 8 + c];
            a0 += bf_lo(w); a1 += bf_hi(w);
        }
        float f0 = (a0 + b0) + (c0 + d0f) + sB[2 * c];
        float f1 = (a1 + b1v) + (c1 + d1f) + sB[2 * c + 1];
        H1u[(size_t)n * 8 + c] = bf_pack(fmaxf(f0, 0.f), fmaxf(f1, 0.f));
    }
}

// ---------------------------------------------------------------------------
// K6: layer-2 aggregation (register accumulation) + fused mm2 epilogue.
// ---------------------------------------------------------------------------
__global__ __launch_bounds__(256) void k_agg2(const int* __restrict__ node_off,
                                              const unsigned* __restrict__ csr,
                                              const unsigned* __restrict__ H1u,
                                              const float* __restrict__ W2,
                                              const float* __restrict__ b2,
                                              float* __restrict__ out) {
    __shared__ float sacc[32][D_HID + 1];
    __shared__ float sW2[D_HID * D_OUT];
    __shared__ float sb2[D_OUT];
    int tid = threadIdx.x;
    for (int i = tid; i < D_HID * D_OUT; i += 256) sW2[i] = W2[i];
    if (tid < D_OUT) sb2[tid] = b2[tid];

    int g = tid >> 3;
    int c = tid & 7;
    int n = blockIdx.x * 32 + g;

    float a0 = 0.f, a1 = 0.f, b0 = 0.f, b1v = 0.f;
    float c0 = 0.f, c1 = 0.f, d0f = 0.f, d1f = 0.f;
    if (n < N_NODES) {
        int beg = node_off[n], end = node_off[n + 1];
        int i = beg;
        for (; i + 3 < end; i += 4) {
            unsigned s0 = csr[i],     s1 = csr[i + 1];
            unsigned s2 = csr[i + 2], s3 = csr[i + 3];
            unsigned w0 = H1u[(size_t)s0 * 8 + c];
            unsigned w1 = H1u[(size_t)s1 * 8 + c];
            unsigned w2 = H1u[(size_t)s2 * 8 + c];
            unsigned w3 = H1u[(size_t)s3 * 8 + c];
            a0 += bf_lo(w0); a1 += bf_hi(w0);
            b0 += bf_lo(w1); b1v += bf_hi(w1);
            c0 += bf_lo(w2); c1 += bf_hi(w2);
            d0f += bf_lo(w3); d1f += bf_hi(w3);
        }
        for (; i < end; ++i) {
            unsigned s = csr[i];
            unsigned w = H1u[(size_t)s * 8 + c];
            a0 += bf_lo(w); a1 += bf_hi(w);
        }
    }
    sacc[g][2 * c]     = (a0 + b0) + (c0 + d0f);
    sacc[g][2 * c + 1] = (a1 + b1v) + (c1 + d1f);
    __syncthreads();

    for (int t = tid; t < 32 * D_OUT; t += 256) {
        int gg = t >> 5, o = t & 31;
        int node = blockIdx.x * 32 + gg;
        if (node < N_NODES) {
            float a = sb2[o];
#pragma unroll
            for (int j = 0; j < D_HID; ++j)
                a = fmaf(sacc[gg][j], sW2[j * D_OUT + o], a);
            out[(size_t)node * D_OUT + o] = a;
        }
    }
}

// ---------------------------------------------------------------------------
extern "C" void kernel_launch(void* const* d_in, const int* in_sizes, int n_in,
                              void* d_out, int out_size, void* d_ws, size_t ws_size,
                              hipStream_t stream) {
    const float* feat = (const float*)d_in[0];
    const int*   src  = (const int*)d_in[1];
    const int*   dst  = (const int*)d_in[2];
    const float* W1   = (const float*)d_in[3];
    const float* b1   = (const float*)d_in[4];
    const float* W2   = (const float*)d_in[5];
    const float* b2   = (const float*)d_in[6];
    float* out = (float*)d_out;

    // ws layout (~18.1 MB, within the proven 19.2 MB footprint):
    //   [0        , 6.4M    )  pairs/csr  (u32, 1.6M)
    //   [6.4M     , 9.6M    )  Yu   (bf16x16 rows, packed dwords)
    //   [9.6M     , 12.8M   )  H1u  (bf16x16 rows, packed dwords)
    //   [12.8M    , +8K     )  colsum   (NB ints)
    //   [+8K      , +16K    )  offsets  (NB+1 ints)
    //   [+16K     , +408K   )  node_off (100033 ints)
    //   [13217792 , +2.44M  )  blockhist (391 x 1563 ints)
    //   [15663104 , +2.44M  )  rowpre    (391 x 1563 ints)
    char* base = (char*)d_ws;
    unsigned* pairs     = (unsigned*)(base);
    unsigned* Yu        = (unsigned*)(base + 6400000);
    unsigned* H1u       = (unsigned*)(base + 9600000);
    int*      colsum    = (int*)(base + 12800000);
    int*      offsets   = (int*)(base + 12808192);
    int*      node_off  = (int*)(base + 12816384);
    int*      blockhist = (int*)(base + 13217792);
    int*      rowpre    = (int*)(base + 15663104);

    // K1: projection + per-block histogram (single pass over dst)
    k_mm1h     <<<SBLOCKS, 256, 0, stream>>>(feat, W1, dst, Yu, blockhist);
    // K2/K3: 2-D prefix -> deterministic placement bases
    k_rowpre   <<<(NB + 255) / 256, 256, 0, stream>>>(blockhist, rowpre, colsum);
    k_scan     <<<1, 256, 0, stream>>>(colsum, offsets);
    // K4: deterministic bucket-grouping sort (no global atomics)
    k_sortplace<<<SBLOCKS, 256, 0, stream>>>(src, dst, offsets, blockhist, rowpre, pairs);
    // K5: node sort + layer-1 aggregation (gathers from LDS-sorted list)
    k_sortagg1 <<<NB, 256, 0, stream>>>(offsets, pairs, Yu, b1, H1u, node_off);
    // K6: layer-2 aggregation + fused mm2
    k_agg2     <<<(N_NODES + 31) / 32, 256, 0, stream>>>(node_off, pairs, H1u, W2, b2, out);
}

// Round 9
// 124.963 us; speedup vs baseline: 1.0195x; 1.0195x over previous
//
#include <hip/hip_runtime.h>
#include <hip/hip_bf16.h>

#define N_NODES 100000
#define N_EDGES 1600000
#define D_IN    128
#define D_HID   16
#define D_OUT   32

#define BSHIFT 6
#define BNODES 64                  // nodes per bucket
#define NB 1563                    // ceil(100000/64)
#define NBPAD2 2048                // scan padding (256 threads x 8)
#define SCHUNK 2048                // edges per sort block (782 blocks -> 3/CU)
#define SBLOCKS 782                // ceil(1600000/2048)
#define SORTCAP 2048               // per-bucket edge cap (mean 1024, sd 32)

// bf16x2 helpers -------------------------------------------------------------
__device__ inline float bf_lo(unsigned dw) { return __uint_as_float(dw << 16); }
__device__ inline float bf_hi(unsigned dw) { return __uint_as_float(dw & 0xffff0000u); }
__device__ inline unsigned bf_pack(float f0, float f1) {
    union { __hip_bfloat16 h[2]; unsigned u; } pu;
    pu.h[0] = __float2bfloat16(f0);
    pu.h[1] = __float2bfloat16(f1);
    return pu.u;
}

// ---------------------------------------------------------------------------
// K1: Y = feat @ W1 -> packed bf16.  4 threads per node (thread = node,jq):
// 400K threads / 1563 blocks -> ~6 blk/CU (vs 391-block thread-per-node grid
// that ran at 14% occupancy / 40us). Lanes 0-3 share the feat float4 load
// (same-address broadcast). Also zeroes counts[] (block b zeros counts[b]),
// ordered before k_hist by stream serialization.
// ---------------------------------------------------------------------------
__global__ __launch_bounds__(256) void k_mm1(const float* __restrict__ feat,
                                             const float* __restrict__ W1,
                                             unsigned* __restrict__ Yu,
                                             int* __restrict__ counts) {
    __shared__ float sW[D_IN * D_HID];  // 8 KB
    int tid = threadIdx.x, blk = blockIdx.x;
    for (int i = tid; i < D_IN * D_HID; i += 256) sW[i] = W1[i];
    if (tid == 0 && blk < NB) counts[blk] = 0;
    __syncthreads();

    int gid = blk * 256 + tid;
    int n = gid >> 2;          // node
    int jq = gid & 3;          // output quad (4 of 16 channels)
    if (n >= N_NODES) return;

    const float4* f4 = (const float4*)(feat + (size_t)n * D_IN);
    const float4* sW4 = (const float4*)sW;

    float4 acc = make_float4(0.f, 0.f, 0.f, 0.f);
#pragma unroll 8
    for (int kq = 0; kq < 32; ++kq) {
        float4 f = f4[kq];
        int k0 = kq * 4;
        float4 w0 = sW4[(k0 + 0) * 4 + jq];
        float4 w1 = sW4[(k0 + 1) * 4 + jq];
        float4 w2 = sW4[(k0 + 2) * 4 + jq];
        float4 w3 = sW4[(k0 + 3) * 4 + jq];
        acc.x += f.x * w0.x + f.y * w1.x + f.z * w2.x + f.w * w3.x;
        acc.y += f.x * w0.y + f.y * w1.y + f.z * w2.y + f.w * w3.y;
        acc.z += f.x * w0.z + f.y * w1.z + f.z * w2.z + f.w * w3.z;
        acc.w += f.x * w0.w + f.y * w1.w + f.z * w2.w + f.w * w3.w;
    }
    uint2 o;
    o.x = bf_pack(acc.x, acc.y);
    o.y = bf_pack(acc.z, acc.w);
    ((uint2*)(Yu + (size_t)n * 8))[jq] = o;
}

// ---------------------------------------------------------------------------
// K2: histogram of dst buckets (LDS pre-aggregation, then global atomics).
// 782 blocks x 2048 edges.
// ---------------------------------------------------------------------------
__global__ __launch_bounds__(256) void k_hist(const int* __restrict__ dst,
                                              int* __restrict__ counts) {
    __shared__ int h[NB];
    int tid = threadIdx.x;
    for (int i = tid; i < NB; i += 256) h[i] = 0;
    __syncthreads();
    int base = blockIdx.x * SCHUNK;
#pragma unroll
    for (int k = 0; k < 8; ++k) {
        int e = base + k * 256 + tid;
        if (e < N_EDGES) atomicAdd(&h[dst[e] >> BSHIFT], 1);
    }
    __syncthreads();
    for (int i = tid; i < NB; i += 256) {
        int c = h[i];
        if (c) atomicAdd(&counts[i], c);
    }
}

// ---------------------------------------------------------------------------
// K3: exclusive scan of NB counts -> offsets[NB+1] and mutable cursor copy.
// ---------------------------------------------------------------------------
__global__ __launch_bounds__(256) void k_scan(const int* __restrict__ counts,
                                              int* __restrict__ offsets,
                                              int* __restrict__ cursor) {
    __shared__ int t[256];
    int tid = threadIdx.x;
    int i0 = tid * 8;
    int v[8];
    int lsum = 0;
#pragma unroll
    for (int m = 0; m < 8; ++m) {
        int idx = i0 + m;
        v[m] = (idx < NB) ? counts[idx] : 0;
        lsum += v[m];
    }
    t[tid] = lsum;
    __syncthreads();
#pragma unroll
    for (int off = 1; off < 256; off <<= 1) {
        int x = (tid >= off) ? t[tid - off] : 0;
        __syncthreads();
        t[tid] += x;
        __syncthreads();
    }
    int excl = t[tid] - lsum;
#pragma unroll
    for (int m = 0; m < 8; ++m) {
        int idx = i0 + m;
        if (idx < NB) { offsets[idx] = excl; cursor[idx] = excl; }
        excl += v[m];
    }
    if (tid == 0) offsets[NB] = N_EDGES;
}

// ---------------------------------------------------------------------------
// K4: block-local counting sort + run-reserved writeout (grouped by bucket).
// pairs[slot] = (src << 6) | (dst & 63). 2048-edge chunks, ~35 KB LDS.
// ---------------------------------------------------------------------------
__global__ __launch_bounds__(256) void k_sortscatter(const int* __restrict__ src,
                                                     const int* __restrict__ dst,
                                                     int* __restrict__ cursor,
                                                     unsigned* __restrict__ pairs) {
    __shared__ int hist[NBPAD2];        // 8 KB, reused as placement counters
    __shared__ int lbase[NBPAD2];       // 8 KB
    __shared__ int gbase[NB];           // 6.25 KB
    __shared__ int tscan[256];          // 1 KB
    __shared__ unsigned sorted[SCHUNK]; // 8 KB
    __shared__ unsigned short bId[SCHUNK]; // 4 KB

    int tid = threadIdx.x;
    int base = blockIdx.x * SCHUNK;
    int nval = N_EDGES - base;
    if (nval > SCHUNK) nval = SCHUNK;

    for (int i = tid; i < NBPAD2; i += 256) hist[i] = 0;
    __syncthreads();

    int varr[8], barr[8];
#pragma unroll
    for (int k = 0; k < 8; ++k) {
        int e = base + k * 256 + tid;
        if (e < N_EDGES) {
            int s = src[e], d = dst[e];
            varr[k] = (s << BSHIFT) | (d & (BNODES - 1));
            int b = d >> BSHIFT;
            barr[k] = b;
            atomicAdd(&hist[b], 1);
        } else {
            barr[k] = -1;
        }
    }
    __syncthreads();

    int i0 = tid * 8;
    int hv[8];
    int lsum = 0;
#pragma unroll
    for (int m = 0; m < 8; ++m) { hv[m] = hist[i0 + m]; lsum += hv[m]; }
    tscan[tid] = lsum;
    __syncthreads();
#pragma unroll
    for (int off = 1; off < 256; off <<= 1) {
        int x = (tid >= off) ? tscan[tid - off] : 0;
        __syncthreads();
        tscan[tid] += x;
        __syncthreads();
    }
    int excl = tscan[tid] - lsum;
#pragma unroll
    for (int m = 0; m < 8; ++m) { lbase[i0 + m] = excl; excl += hv[m]; }
    __syncthreads();

    for (int i = tid; i < NB; i += 256) {
        int c = hist[i];
        if (c > 0) gbase[i] = atomicAdd(&cursor[i], c);
    }
    __syncthreads();
    for (int i = tid; i < NBPAD2; i += 256) hist[i] = 0;   // -> placement cnt
    __syncthreads();

#pragma unroll
    for (int k = 0; k < 8; ++k) {
        int b = barr[k];
        if (b >= 0) {
            int r = atomicAdd(&hist[b], 1);
            int p = lbase[b] + r;
            sorted[p] = (unsigned)varr[k];
            bId[p] = (unsigned short)b;
        }
    }
    __syncthreads();

    for (int i = tid; i < nval; i += 256) {
        int b = bId[i];
        pairs[gbase[b] + (i - lbase[b])] = sorted[i];
    }
}

// ---------------------------------------------------------------------------
// K5: fused per-bucket node sort + layer-1 aggregation. Sorts the bucket's
// edges by dst node in LDS, writes node_off + csr (for agg2), then gathers Y
// straight from the LDS-sorted src list with register accumulation.
// Fused bias+ReLU -> packed bf16 H1.
// ---------------------------------------------------------------------------
__global__ __launch_bounds__(256) void k_sortagg1(const int* __restrict__ offsets,
                                                  unsigned* __restrict__ pairs,
                                                  const unsigned* __restrict__ Yu,
                                                  const float* __restrict__ bias1,
                                                  unsigned* __restrict__ H1u,
                                                  int* __restrict__ node_off) {
    __shared__ unsigned buf[SORTCAP];   // 8 KB
    __shared__ unsigned sbuf[SORTCAP];  // 8 KB
    __shared__ int hist[BNODES];
    __shared__ int lbase[BNODES];
    __shared__ int cur[BNODES];
    __shared__ float sB[D_HID];
    int tid = threadIdx.x, b = blockIdx.x;
    int beg = offsets[b], end = offsets[b + 1];
    int cnt = end - beg;
    if (cnt > SORTCAP) cnt = SORTCAP;
    if (tid < BNODES) hist[tid] = 0;
    if (tid < D_HID) sB[tid] = bias1[tid];
    __syncthreads();

    for (int i = tid; i < cnt; i += 256) {
        unsigned p = pairs[beg + i];
        buf[i] = p;
        atomicAdd(&hist[p & (BNODES - 1)], 1);
    }
    __syncthreads();

    if (tid == 0) {
        int run = 0;
#pragma unroll
        for (int l = 0; l < BNODES; ++l) {
            lbase[l] = run;
            cur[l] = run;
            run += hist[l];
        }
    }
    __syncthreads();

    if (tid < BNODES) node_off[b * BNODES + tid] = beg + lbase[tid];
    if (b == 0 && tid == 0) node_off[NB * BNODES] = N_EDGES;

    for (int i = tid; i < cnt; i += 256) {
        unsigned p = buf[i];
        int pos = atomicAdd(&cur[p & (BNODES - 1)], 1);
        unsigned sid = p >> BSHIFT;
        sbuf[pos] = sid;
        pairs[beg + pos] = sid;     // global csr for agg2
    }
    __syncthreads();

    // gather-accumulate: 8 lanes per node, 2 nodes per 8-lane group
    int c = tid & 7;
    int grp = tid >> 3;
#pragma unroll
    for (int rep = 0; rep < 2; ++rep) {
        int ln = grp * 2 + rep;
        int n = b * BNODES + ln;
        if (n >= N_NODES) continue;
        int s = lbase[ln], e = cur[ln];   // cur = lbase + count after placement
        float a0 = 0.f, a1 = 0.f, b0 = 0.f, b1v = 0.f;
        float c0 = 0.f, c1 = 0.f, d0f = 0.f, d1f = 0.f;
        int i = s;
        for (; i + 3 < e; i += 4) {
            unsigned w0 = Yu[(size_t)sbuf[i]     * 8 + c];
            unsigned w1 = Yu[(size_t)sbuf[i + 1] * 8 + c];
            unsigned w2 = Yu[(size_t)sbuf[i + 2] * 8 + c];
            unsigned w3 = Yu[(size_t)sbuf[i + 3] * 8 + c];
            a0 += bf_lo(w0); a1 += bf_hi(w0);
            b0 += bf_lo(w1); b1v += bf_hi(w1);
            c0 += bf_lo(w2); c1 += bf_hi(w2);
            d0f += bf_lo(w3); d1f += bf_hi(w3);
        }
        for (; i < e; ++i) {
            unsigned w = Yu[(size_t)sbuf[i] * 8 + c];
            a0 += bf_lo(w); a1 += bf_hi(w);
        }
        float f0 = (a0 + b0) + (c0 + d0f) + sB[2 * c];
        float f1 = (a1 + b1v) + (c1 + d1f) + sB[2 * c + 1];
        H1u[(size_t)n * 8 + c] = bf_pack(fmaxf(f0, 0.f), fmaxf(f1, 0.f));
    }
}

// ---------------------------------------------------------------------------
// K6: layer-2 aggregation (register accumulation) + fused mm2 epilogue.
// ---------------------------------------------------------------------------
__global__ __launch_bounds__(256) void k_agg2(const int* __restrict__ node_off,
                                              const unsigned* __restrict__ csr,
                                              const unsigned* __restrict__ H1u,
                                              const float* __restrict__ W2,
                                              const float* __restrict__ b2,
                                              float* __restrict__ out) {
    __shared__ float sacc[32][D_HID + 1];
    __shared__ float sW2[D_HID * D_OUT];
    __shared__ float sb2[D_OUT];
    int tid = threadIdx.x;
    for (int i = tid; i < D_HID * D_OUT; i += 256) sW2[i] = W2[i];
    if (tid < D_OUT) sb2[tid] = b2[tid];

    int g = tid >> 3;
    int c = tid & 7;
    int n = blockIdx.x * 32 + g;

    float a0 = 0.f, a1 = 0.f, b0 = 0.f, b1v = 0.f;
    float c0 = 0.f, c1 = 0.f, d0f = 0.f, d1f = 0.f;
    if (n < N_NODES) {
        int beg = node_off[n], end = node_off[n + 1];
        int i = beg;
        for (; i + 3 < end; i += 4) {
            unsigned s0 = csr[i],     s1 = csr[i + 1];
            unsigned s2 = csr[i + 2], s3 = csr[i + 3];
            unsigned w0 = H1u[(size_t)s0 * 8 + c];
            unsigned w1 = H1u[(size_t)s1 * 8 + c];
            unsigned w2 = H1u[(size_t)s2 * 8 + c];
            unsigned w3 = H1u[(size_t)s3 * 8 + c];
            a0 += bf_lo(w0); a1 += bf_hi(w0);
            b0 += bf_lo(w1); b1v += bf_hi(w1);
            c0 += bf_lo(w2); c1 += bf_hi(w2);
            d0f += bf_lo(w3); d1f += bf_hi(w3);
        }
        for (; i < end; ++i) {
            unsigned s = csr[i];
            unsigned w = H1u[(size_t)s * 8 + c];
            a0 += bf_lo(w); a1 += bf_hi(w);
        }
    }
    sacc[g][2 * c]     = (a0 + b0) + (c0 + d0f);
    sacc[g][2 * c + 1] = (a1 + b1v) + (c1 + d1f);
    __syncthreads();

    for (int t = tid; t < 32 * D_OUT; t += 256) {
        int gg = t >> 5, o = t & 31;
        int node = blockIdx.x * 32 + gg;
        if (node < N_NODES) {
            float a = sb2[o];
#pragma unroll
            for (int j = 0; j < D_HID; ++j)
                a = fmaf(sacc[gg][j], sW2[j * D_OUT + o], a);
            out[(size_t)node * D_OUT + o] = a;
        }
    }
}

// ---------------------------------------------------------------------------
extern "C" void kernel_launch(void* const* d_in, const int* in_sizes, int n_in,
                              void* d_out, int out_size, void* d_ws, size_t ws_size,
                              hipStream_t stream) {
    const float* feat = (const float*)d_in[0];
    const int*   src  = (const int*)d_in[1];
    const int*   dst  = (const int*)d_in[2];
    const float* W1   = (const float*)d_in[3];
    const float* b1   = (const float*)d_in[4];
    const float* W2   = (const float*)d_in[5];
    const float* b2   = (const float*)d_in[6];
    float* out = (float*)d_out;

    // ws layout (~13.2 MB):
    //   [0      , 6.4M )  pairs/csr (u32, 1.6M)
    //   [6.4M   , 9.6M )  Yu   (bf16x16 rows, packed dwords)
    //   [9.6M   , 12.8M)  H1u  (bf16x16 rows, packed dwords)
    //   [12.8M  , +8K  )  counts  (NB ints)
    //   [+8K    , +16K )  offsets (NB+1 ints)
    //   [+16K   , +24K )  cursor  (NB ints)
    //   [+24K   , +424K)  node_off (NB*64+1 ints = 100033)
    char* base = (char*)d_ws;
    unsigned* pairs    = (unsigned*)(base);
    unsigned* Yu       = (unsigned*)(base + 6400000);
    unsigned* H1u      = (unsigned*)(base + 9600000);
    int*      counts   = (int*)(base + 12800000);
    int*      offsets  = (int*)(base + 12800000 + 8192);
    int*      cursor   = (int*)(base + 12800000 + 16384);
    int*      node_off = (int*)(base + 12800000 + 24576);

    // K1: projection (4 thr/node, 1563 blocks) + counts zeroing
    k_mm1        <<<(N_NODES * 4 + 255) / 256, 256, 0, stream>>>(feat, W1, Yu, counts);
    // K2-K4: CSR build (bucket-grouping counting sort)
    k_hist       <<<SBLOCKS, 256, 0, stream>>>(dst, counts);
    k_scan       <<<1, 256, 0, stream>>>(counts, offsets, cursor);
    k_sortscatter<<<SBLOCKS, 256, 0, stream>>>(src, dst, cursor, pairs);
    // K5: node sort + layer-1 aggregation (fused bias+ReLU)
    k_sortagg1   <<<NB, 256, 0, stream>>>(offsets, pairs, Yu, b1, H1u, node_off);
    // K6: layer-2 aggregation + fused mm2
    k_agg2       <<<(N_NODES + 31) / 32, 256, 0, stream>>>(node_off, pairs, H1u, W2, b2, out);
}

// Round 10
// 109.115 us; speedup vs baseline: 1.1676x; 1.1452x over previous
//
#include <hip/hip_runtime.h>
#include <hip/hip_bf16.h>

#define N_NODES 100000
#define N_EDGES 1600000
#define D_IN    128
#define D_HID   16
#define D_OUT   32

#define BSHIFT 8
#define BNODES 256                 // nodes per bucket
#define NB 391                     // ceil(100000/256)
#define NBPAD 512                  // scan padding (256 threads x 2)
#define SCHUNK 4096                // edges per sort block
#define SBLOCKS 391                // ceil(1600000/4096)
#define SORTCAP 4608               // per-bucket cap (mean 4096, sd 64 -> +8 sigma)

// bf16x2 helpers -------------------------------------------------------------
__device__ inline float bf_lo(unsigned dw) { return __uint_as_float(dw << 16); }
__device__ inline float bf_hi(unsigned dw) { return __uint_as_float(dw & 0xffff0000u); }
__device__ inline unsigned bf_pack(float f0, float f1) {
    union { __hip_bfloat16 h[2]; unsigned u; } pu;
    pu.h[0] = __float2bfloat16(f0);
    pu.h[1] = __float2bfloat16(f1);
    return pu.u;
}

// ---------------------------------------------------------------------------
// K1: Y = feat @ W1 -> packed bf16. 4 threads/node (proven in round 9).
// Also zeroes counts[] (block b zeros counts[b], b < NB).
// ---------------------------------------------------------------------------
__global__ __launch_bounds__(256) void k_mm1(const float* __restrict__ feat,
                                             const float* __restrict__ W1,
                                             unsigned* __restrict__ Yu,
                                             int* __restrict__ counts) {
    __shared__ float sW[D_IN * D_HID];  // 8 KB
    int tid = threadIdx.x, blk = blockIdx.x;
    for (int i = tid; i < D_IN * D_HID; i += 256) sW[i] = W1[i];
    if (tid == 0 && blk < NB) counts[blk] = 0;
    __syncthreads();

    int gid = blk * 256 + tid;
    int n = gid >> 2;          // node
    int jq = gid & 3;          // output quad
    if (n >= N_NODES) return;

    const float4* f4 = (const float4*)(feat + (size_t)n * D_IN);
    const float4* sW4 = (const float4*)sW;

    float4 acc = make_float4(0.f, 0.f, 0.f, 0.f);
#pragma unroll 8
    for (int kq = 0; kq < 32; ++kq) {
        float4 f = f4[kq];
        int k0 = kq * 4;
        float4 w0 = sW4[(k0 + 0) * 4 + jq];
        float4 w1 = sW4[(k0 + 1) * 4 + jq];
        float4 w2 = sW4[(k0 + 2) * 4 + jq];
        float4 w3 = sW4[(k0 + 3) * 4 + jq];
        acc.x += f.x * w0.x + f.y * w1.x + f.z * w2.x + f.w * w3.x;
        acc.y += f.x * w0.y + f.y * w1.y + f.z * w2.y + f.w * w3.y;
        acc.z += f.x * w0.z + f.y * w1.z + f.z * w2.z + f.w * w3.z;
        acc.w += f.x * w0.w + f.y * w1.w + f.z * w2.w + f.w * w3.w;
    }
    uint2 o;
    o.x = bf_pack(acc.x, acc.y);
    o.y = bf_pack(acc.z, acc.w);
    ((uint2*)(Yu + (size_t)n * 8))[jq] = o;
}

// ---------------------------------------------------------------------------
// K2: histogram of dst buckets (LDS pre-aggregation, then global atomics).
// 391 blocks x 4096 edges; only 391x391 = 153K global atomics.
// ---------------------------------------------------------------------------
__global__ __launch_bounds__(256) void k_hist(const int* __restrict__ dst,
                                              int* __restrict__ counts) {
    __shared__ int h[NB];
    int tid = threadIdx.x;
    for (int i = tid; i < NB; i += 256) h[i] = 0;
    __syncthreads();
    int base = blockIdx.x * SCHUNK;
#pragma unroll
    for (int k = 0; k < 16; ++k) {
        int e = base + k * 256 + tid;
        if (e < N_EDGES) atomicAdd(&h[dst[e] >> BSHIFT], 1);
    }
    __syncthreads();
    for (int i = tid; i < NB; i += 256) {
        int c = h[i];
        if (c) atomicAdd(&counts[i], c);
    }
}

// ---------------------------------------------------------------------------
// K3: exclusive scan of NB counts -> offsets[NB+1] and mutable cursor copy.
// 256 threads x 2 elems (stride-2 LDS: conflict-free).
// ---------------------------------------------------------------------------
__global__ __launch_bounds__(256) void k_scan(const int* __restrict__ counts,
                                              int* __restrict__ offsets,
                                              int* __restrict__ cursor) {
    __shared__ int t[256];
    int tid = threadIdx.x;
    int i0 = tid * 2;
    int v0 = (i0 + 0 < NB) ? counts[i0 + 0] : 0;
    int v1 = (i0 + 1 < NB) ? counts[i0 + 1] : 0;
    int lsum = v0 + v1;
    t[tid] = lsum;
    __syncthreads();
#pragma unroll
    for (int off = 1; off < 256; off <<= 1) {
        int x = (tid >= off) ? t[tid - off] : 0;
        __syncthreads();
        t[tid] += x;
        __syncthreads();
    }
    int excl = t[tid] - lsum;
    if (i0 + 0 < NB) { offsets[i0 + 0] = excl;      cursor[i0 + 0] = excl;      }
    if (i0 + 1 < NB) { offsets[i0 + 1] = excl + v0; cursor[i0 + 1] = excl + v0; }
    if (tid == 0) offsets[NB] = N_EDGES;
}

// ---------------------------------------------------------------------------
// K4: block-local counting sort + run-reserved writeout (256-node buckets).
// Runs average 10.5 edges (42B) -> mostly-contiguous global writes.
// pairs[slot] = (src << 8) | (dst & 255).
// ---------------------------------------------------------------------------
__global__ __launch_bounds__(256) void k_sortscatter(const int* __restrict__ src,
                                                     const int* __restrict__ dst,
                                                     int* __restrict__ cursor,
                                                     unsigned* __restrict__ pairs) {
    __shared__ int hist[NBPAD];         // 2 KB, reused as placement counters
    __shared__ int lbase[NBPAD];        // 2 KB
    __shared__ int gbase[NB];           // 1.6 KB
    __shared__ int tscan[256];          // 1 KB
    __shared__ unsigned sorted[SCHUNK]; // 16 KB
    __shared__ unsigned short bId[SCHUNK]; // 8 KB  (~31 KB -> 5 blk/CU cap)

    int tid = threadIdx.x;
    int base = blockIdx.x * SCHUNK;
    int nval = N_EDGES - base;
    if (nval > SCHUNK) nval = SCHUNK;

    for (int i = tid; i < NBPAD; i += 256) hist[i] = 0;
    __syncthreads();

    int varr[16], barr[16];
#pragma unroll
    for (int k = 0; k < 16; ++k) {
        int e = base + k * 256 + tid;
        if (e < N_EDGES) {
            int s = src[e], d = dst[e];
            varr[k] = (s << BSHIFT) | (d & (BNODES - 1));
            int b = d >> BSHIFT;
            barr[k] = b;
            atomicAdd(&hist[b], 1);
        } else {
            barr[k] = -1;
        }
    }
    __syncthreads();

    // scan hist -> lbase (2 elems/thread, stride-2: conflict-free)
    int i0 = tid * 2;
    int h0 = hist[i0], h1 = hist[i0 + 1];
    int lsum = h0 + h1;
    tscan[tid] = lsum;
    __syncthreads();
#pragma unroll
    for (int off = 1; off < 256; off <<= 1) {
        int x = (tid >= off) ? tscan[tid - off] : 0;
        __syncthreads();
        tscan[tid] += x;
        __syncthreads();
    }
    int excl = tscan[tid] - lsum;
    lbase[i0 + 0] = excl;
    lbase[i0 + 1] = excl + h0;
    __syncthreads();

    // reserve global run space (<=1 atomic per bucket per block)
    for (int i = tid; i < NB; i += 256) {
        int c = hist[i];
        if (c > 0) gbase[i] = atomicAdd(&cursor[i], c);
    }
    __syncthreads();
    for (int i = tid; i < NBPAD; i += 256) hist[i] = 0;   // -> placement cnt
    __syncthreads();

#pragma unroll
    for (int k = 0; k < 16; ++k) {
        int b = barr[k];
        if (b >= 0) {
            int r = atomicAdd(&hist[b], 1);
            int p = lbase[b] + r;
            sorted[p] = (unsigned)varr[k];
            bId[p] = (unsigned short)b;
        }
    }
    __syncthreads();

    // writeout in sorted order: ~10.5-edge runs -> contiguous addresses
    for (int i = tid; i < nval; i += 256) {
        int b = bId[i];
        pairs[gbase[b] + (i - lbase[b])] = sorted[i];
    }
}

// ---------------------------------------------------------------------------
// K5: per-bucket node sort (256 keys, 1 thread per key). In-place rewrite of
// pairs -> node-sorted plain src ids + node_off emission.
// ---------------------------------------------------------------------------
__global__ __launch_bounds__(256) void k_nodesort(const int* __restrict__ offsets,
                                                  unsigned* __restrict__ pairs,
                                                  int* __restrict__ node_off) {
    __shared__ unsigned buf[SORTCAP];   // 18 KB
    __shared__ int hist[BNODES];
    __shared__ int cur[BNODES];
    __shared__ int t[256];

    int tid = threadIdx.x, b = blockIdx.x;
    int beg = offsets[b], end = offsets[b + 1];
    int cnt = end - beg;
    if (cnt > SORTCAP) cnt = SORTCAP;

    hist[tid] = 0;
    __syncthreads();

    for (int i = tid; i < cnt; i += 256) {
        unsigned p = pairs[beg + i];
        buf[i] = p;
        atomicAdd(&hist[p & (BNODES - 1)], 1);
    }
    __syncthreads();

    // parallel exclusive scan: thread tid owns key tid (1:1)
    int v = hist[tid];
    t[tid] = v;
    __syncthreads();
#pragma unroll
    for (int off = 1; off < 256; off <<= 1) {
        int x = (tid >= off) ? t[tid - off] : 0;
        __syncthreads();
        t[tid] += x;
        __syncthreads();
    }
    int excl = t[tid] - v;
    cur[tid] = excl;
    node_off[b * BNODES + tid] = beg + excl;
    if (b == 0 && tid == 0) node_off[NB * BNODES] = N_EDGES;
    __syncthreads();

    for (int i = tid; i < cnt; i += 256) {
        unsigned p = buf[i];
        int pos = atomicAdd(&cur[p & (BNODES - 1)], 1);
        pairs[beg + pos] = p >> BSHIFT;    // plain src id, node-sorted
    }
}

// ---------------------------------------------------------------------------
// K6: layer-1 aggregation: 32 nodes/block, 8 lanes/node, register accum,
// 4 independent gather chains; fused bias+ReLU -> packed bf16 H1.
// ---------------------------------------------------------------------------
__global__ __launch_bounds__(256) void k_agg1(const int* __restrict__ node_off,
                                              const unsigned* __restrict__ csr,
                                              const unsigned* __restrict__ Yu,
                                              const float* __restrict__ bias1,
                                              unsigned* __restrict__ H1u) {
    int tid = threadIdx.x;
    int g = tid >> 3;
    int c = tid & 7;
    int n = blockIdx.x * 32 + g;
    if (n >= N_NODES) return;

    int beg = node_off[n], end = node_off[n + 1];
    float a0 = 0.f, a1 = 0.f, b0 = 0.f, b1v = 0.f;
    float c0 = 0.f, c1 = 0.f, d0f = 0.f, d1f = 0.f;
    int i = beg;
    for (; i + 3 < end; i += 4) {
        unsigned w0 = Yu[(size_t)csr[i]     * 8 + c];
        unsigned w1 = Yu[(size_t)csr[i + 1] * 8 + c];
        unsigned w2 = Yu[(size_t)csr[i + 2] * 8 + c];
        unsigned w3 = Yu[(size_t)csr[i + 3] * 8 + c];
        a0 += bf_lo(w0); a1 += bf_hi(w0);
        b0 += bf_lo(w1); b1v += bf_hi(w1);
        c0 += bf_lo(w2); c1 += bf_hi(w2);
        d0f += bf_lo(w3); d1f += bf_hi(w3);
    }
    for (; i < end; ++i) {
        unsigned w = Yu[(size_t)csr[i] * 8 + c];
        a0 += bf_lo(w); a1 += bf_hi(w);
    }
    float f0 = (a0 + b0) + (c0 + d0f) + bias1[2 * c];
    float f1 = (a1 + b1v) + (c1 + d1f) + bias1[2 * c + 1];
    H1u[(size_t)n * 8 + c] = bf_pack(fmaxf(f0, 0.f), fmaxf(f1, 0.f));
}

// ---------------------------------------------------------------------------
// K7: layer-2 aggregation (register accumulation) + fused mm2 epilogue.
// ---------------------------------------------------------------------------
__global__ __launch_bounds__(256) void k_agg2(const int* __restrict__ node_off,
                                              const unsigned* __restrict__ csr,
                                              const unsigned* __restrict__ H1u,
                                              const float* __restrict__ W2,
                                              const float* __restrict__ b2,
                                              float* __restrict__ out) {
    __shared__ float sacc[32][D_HID + 1];
    __shared__ float sW2[D_HID * D_OUT];
    __shared__ float sb2[D_OUT];
    int tid = threadIdx.x;
    for (int i = tid; i < D_HID * D_OUT; i += 256) sW2[i] = W2[i];
    if (tid < D_OUT) sb2[tid] = b2[tid];

    int g = tid >> 3;
    int c = tid & 7;
    int n = blockIdx.x * 32 + g;

    float a0 = 0.f, a1 = 0.f, b0 = 0.f, b1v = 0.f;
    float c0 = 0.f, c1 = 0.f, d0f = 0.f, d1f = 0.f;
    if (n < N_NODES) {
        int beg = node_off[n], end = node_off[n + 1];
        int i = beg;
        for (; i + 3 < end; i += 4) {
            unsigned w0 = H1u[(size_t)csr[i]     * 8 + c];
            unsigned w1 = H1u[(size_t)csr[i + 1] * 8 + c];
            unsigned w2 = H1u[(size_t)csr[i + 2] * 8 + c];
            unsigned w3 = H1u[(size_t)csr[i + 3] * 8 + c];
            a0 += bf_lo(w0); a1 += bf_hi(w0);
            b0 += bf_lo(w1); b1v += bf_hi(w1);
            c0 += bf_lo(w2); c1 += bf_hi(w2);
            d0f += bf_lo(w3); d1f += bf_hi(w3);
        }
        for (; i < end; ++i) {
            unsigned w = H1u[(size_t)csr[i] * 8 + c];
            a0 += bf_lo(w); a1 += bf_hi(w);
        }
    }
    sacc[g][2 * c]     = (a0 + b0) + (c0 + d0f);
    sacc[g][2 * c + 1] = (a1 + b1v) + (c1 + d1f);
    __syncthreads();

    for (int t = tid; t < 32 * D_OUT; t += 256) {
        int gg = t >> 5, o = t & 31;
        int node = blockIdx.x * 32 + gg;
        if (node < N_NODES) {
            float a = sb2[o];
#pragma unroll
            for (int j = 0; j < D_HID; ++j)
                a = fmaf(sacc[gg][j], sW2[j * D_OUT + o], a);
            out[(size_t)node * D_OUT + o] = a;
        }
    }
}

// ---------------------------------------------------------------------------
extern "C" void kernel_launch(void* const* d_in, const int* in_sizes, int n_in,
                              void* d_out, int out_size, void* d_ws, size_t ws_size,
                              hipStream_t stream) {
    const float* feat = (const float*)d_in[0];
    const int*   src  = (const int*)d_in[1];
    const int*   dst  = (const int*)d_in[2];
    const float* W1   = (const float*)d_in[3];
    const float* b1   = (const float*)d_in[4];
    const float* W2   = (const float*)d_in[5];
    const float* b2   = (const float*)d_in[6];
    float* out = (float*)d_out;

    // ws layout (~13.2 MB):
    //   [0      , 6.4M )  pairs/csr (u32, 1.6M)
    //   [6.4M   , 9.6M )  Yu   (bf16x16 rows, packed dwords)
    //   [9.6M   , 12.8M)  H1u  (bf16x16 rows, packed dwords)
    //   [12.8M  , +8K  )  counts  (NB ints)
    //   [+8K    , +16K )  offsets (NB+1 ints)
    //   [+16K   , +24K )  cursor  (NB ints)
    //   [+24K   , +425K)  node_off (NB*256+1 = 100097 ints)
    char* base = (char*)d_ws;
    unsigned* pairs    = (unsigned*)(base);
    unsigned* Yu       = (unsigned*)(base + 6400000);
    unsigned* H1u      = (unsigned*)(base + 9600000);
    int*      counts   = (int*)(base + 12800000);
    int*      offsets  = (int*)(base + 12800000 + 8192);
    int*      cursor   = (int*)(base + 12800000 + 16384);
    int*      node_off = (int*)(base + 12800000 + 24576);

    // K1: projection (4 thr/node) + counts zeroing
    k_mm1        <<<(N_NODES * 4 + 255) / 256, 256, 0, stream>>>(feat, W1, Yu, counts);
    // K2-K4: bucket-grouping counting sort (256-node buckets, 10.5-edge runs)
    k_hist       <<<SBLOCKS, 256, 0, stream>>>(dst, counts);
    k_scan       <<<1, 256, 0, stream>>>(counts, offsets, cursor);
    k_sortscatter<<<SBLOCKS, 256, 0, stream>>>(src, dst, cursor, pairs);
    // K5: per-bucket node sort -> csr + node_off
    k_nodesort   <<<NB, 256, 0, stream>>>(offsets, pairs, node_off);
    // K6: layer-1 aggregation (fused bias+ReLU)
    k_agg1       <<<(N_NODES + 31) / 32, 256, 0, stream>>>(node_off, pairs, Yu, b1, H1u);
    // K7: layer-2 aggregation + fused mm2
    k_agg2       <<<(N_NODES + 31) / 32, 256, 0, stream>>>(node_off, pairs, H1u, W2, b2, out);
}

// Round 11
// 91.506 us; speedup vs baseline: 1.3923x; 1.1924x over previous
//
#include <hip/hip_runtime.h>
#include <hip/hip_bf16.h>

#define N_NODES 100000
#define N_EDGES 1600000
#define D_IN    128
#define D_HID   16
#define D_OUT   32

#define BSHIFT 8
#define BNODES 256                 // nodes per bucket
#define NB 391                     // ceil(100000/256)
#define NBPAD 512                  // scan padding (256 threads x 2)
#define SCHUNK 4096                // edges per sort block
#define SBLOCKS 391                // ceil(1600000/4096)
#define SLAB 4608                  // slab slots per bucket (mean 4096, +8 sigma)
#define NOSTRIDE 257               // node_off stride per bucket (256 + sentinel)

// bf16x2 helpers -------------------------------------------------------------
__device__ inline float bf_lo(unsigned dw) { return __uint_as_float(dw << 16); }
__device__ inline float bf_hi(unsigned dw) { return __uint_as_float(dw & 0xffff0000u); }
__device__ inline unsigned bf_pack(float f0, float f1) {
    union { __hip_bfloat16 h[2]; unsigned u; } pu;
    pu.h[0] = __float2bfloat16(f0);
    pu.h[1] = __float2bfloat16(f1);
    return pu.u;
}
__device__ inline void acc4(float* a, uint2 w) {
    a[0] += bf_lo(w.x); a[1] += bf_hi(w.x);
    a[2] += bf_lo(w.y); a[3] += bf_hi(w.y);
}

// ---------------------------------------------------------------------------
// K1: Y = feat @ W1 -> packed bf16 (4 threads/node, proven). Also initializes
// the slab cursors (cursor[b] = b*SLAB) -- race-free, sortscatter is 2 kernels
// later. No counts array, no hist, no scan anywhere in the pipeline.
// ---------------------------------------------------------------------------
__global__ __launch_bounds__(256) void k_mm1(const float* __restrict__ feat,
                                             const float* __restrict__ W1,
                                             unsigned* __restrict__ Yu,
                                             int* __restrict__ cursor) {
    __shared__ float sW[D_IN * D_HID];  // 8 KB
    int tid = threadIdx.x, blk = blockIdx.x;
    for (int i = tid; i < D_IN * D_HID; i += 256) sW[i] = W1[i];
    if (tid == 0 && blk < NB) cursor[blk] = blk * SLAB;
    __syncthreads();

    int gid = blk * 256 + tid;
    int n = gid >> 2;          // node
    int jq = gid & 3;          // output quad
    if (n >= N_NODES) return;

    const float4* f4 = (const float4*)(feat + (size_t)n * D_IN);
    const float4* sW4 = (const float4*)sW;

    float4 acc = make_float4(0.f, 0.f, 0.f, 0.f);
#pragma unroll 8
    for (int kq = 0; kq < 32; ++kq) {
        float4 f = f4[kq];
        int k0 = kq * 4;
        float4 w0 = sW4[(k0 + 0) * 4 + jq];
        float4 w1 = sW4[(k0 + 1) * 4 + jq];
        float4 w2 = sW4[(k0 + 2) * 4 + jq];
        float4 w3 = sW4[(k0 + 3) * 4 + jq];
        acc.x += f.x * w0.x + f.y * w1.x + f.z * w2.x + f.w * w3.x;
        acc.y += f.x * w0.y + f.y * w1.y + f.z * w2.y + f.w * w3.y;
        acc.z += f.x * w0.z + f.y * w1.z + f.z * w2.z + f.w * w3.z;
        acc.w += f.x * w0.w + f.y * w1.w + f.z * w2.w + f.w * w3.w;
    }
    uint2 o;
    o.x = bf_pack(acc.x, acc.y);
    o.y = bf_pack(acc.z, acc.w);
    ((uint2*)(Yu + (size_t)n * 8))[jq] = o;
}

// ---------------------------------------------------------------------------
// K2: block-local counting sort + run-reserved slab writeout. Runs average
// ~10.5 edges -> mostly-contiguous global writes. pairs slot layout: bucket b
// owns [b*SLAB, b*SLAB + cnt_b). pairs value = (src << 8) | (dst & 255).
// ---------------------------------------------------------------------------
__global__ __launch_bounds__(256) void k_sortscatter(const int* __restrict__ src,
                                                     const int* __restrict__ dst,
                                                     int* __restrict__ cursor,
                                                     unsigned* __restrict__ pairs) {
    __shared__ int hist[NBPAD];         // 2 KB, reused as placement counters
    __shared__ int lbase[NBPAD];        // 2 KB
    __shared__ int gbase[NB];           // 1.6 KB
    __shared__ int tscan[256];          // 1 KB
    __shared__ unsigned sorted[SCHUNK]; // 16 KB
    __shared__ unsigned short bId[SCHUNK]; // 8 KB  (~31 KB)

    int tid = threadIdx.x;
    int base = blockIdx.x * SCHUNK;
    int nval = N_EDGES - base;
    if (nval > SCHUNK) nval = SCHUNK;

    for (int i = tid; i < NBPAD; i += 256) hist[i] = 0;
    __syncthreads();

    int varr[16], barr[16];
#pragma unroll
    for (int k = 0; k < 16; ++k) {
        int e = base + k * 256 + tid;
        if (e < N_EDGES) {
            int s = src[e], d = dst[e];
            varr[k] = (s << BSHIFT) | (d & (BNODES - 1));
            int b = d >> BSHIFT;
            barr[k] = b;
            atomicAdd(&hist[b], 1);
        } else {
            barr[k] = -1;
        }
    }
    __syncthreads();

    // scan hist -> lbase (2 elems/thread, stride-2: conflict-free)
    int i0 = tid * 2;
    int h0 = hist[i0], h1 = hist[i0 + 1];
    int lsum = h0 + h1;
    tscan[tid] = lsum;
    __syncthreads();
#pragma unroll
    for (int off = 1; off < 256; off <<= 1) {
        int x = (tid >= off) ? tscan[tid - off] : 0;
        __syncthreads();
        tscan[tid] += x;
        __syncthreads();
    }
    int excl = tscan[tid] - lsum;
    lbase[i0 + 0] = excl;
    lbase[i0 + 1] = excl + h0;
    __syncthreads();

    // reserve slab run space (<=1 atomic per bucket per block)
    for (int i = tid; i < NB; i += 256) {
        int c = hist[i];
        if (c > 0) gbase[i] = atomicAdd(&cursor[i], c);
    }
    __syncthreads();
    for (int i = tid; i < NBPAD; i += 256) hist[i] = 0;   // -> placement cnt
    __syncthreads();

#pragma unroll
    for (int k = 0; k < 16; ++k) {
        int b = barr[k];
        if (b >= 0) {
            int r = atomicAdd(&hist[b], 1);
            int p = lbase[b] + r;
            sorted[p] = (unsigned)varr[k];
            bId[p] = (unsigned short)b;
        }
    }
    __syncthreads();

    for (int i = tid; i < nval; i += 256) {
        int b = bId[i];
        pairs[gbase[b] + (i - lbase[b])] = sorted[i];
    }
}

// ---------------------------------------------------------------------------
// K3: per-bucket node sort (256 keys, 1 thread per key). Reads cnt from the
// final slab cursor, rewrites pairs in place as node-sorted plain src ids,
// emits node_off with per-bucket stride 257 (index = n + (n>>8)).
// ---------------------------------------------------------------------------
__global__ __launch_bounds__(256) void k_nodesort(const int* __restrict__ cursor,
                                                  unsigned* __restrict__ pairs,
                                                  int* __restrict__ node_off) {
    __shared__ unsigned buf[SLAB];      // 18 KB
    __shared__ int hist[BNODES];
    __shared__ int cur[BNODES];
    __shared__ int t[256];

    int tid = threadIdx.x, b = blockIdx.x;
    int beg = b * SLAB;
    int cnt = cursor[b] - beg;

    hist[tid] = 0;
    __syncthreads();

    for (int i = tid; i < cnt; i += 256) {
        unsigned p = pairs[beg + i];
        buf[i] = p;
        atomicAdd(&hist[p & (BNODES - 1)], 1);
    }
    __syncthreads();

    int v = hist[tid];
    t[tid] = v;
    __syncthreads();
#pragma unroll
    for (int off = 1; off < 256; off <<= 1) {
        int x = (tid >= off) ? t[tid - off] : 0;
        __syncthreads();
        t[tid] += x;
        __syncthreads();
    }
    int excl = t[tid] - v;
    cur[tid] = excl;
    node_off[b * NOSTRIDE + tid] = beg + excl;
    if (tid == 0) node_off[b * NOSTRIDE + BNODES] = beg + cnt;  // sentinel
    __syncthreads();

    for (int i = tid; i < cnt; i += 256) {
        unsigned p = buf[i];
        int pos = atomicAdd(&cur[p & (BNODES - 1)], 1);
        pairs[beg + pos] = p >> BSHIFT;    // plain src id, node-sorted
    }
}

// ---------------------------------------------------------------------------
// K4: layer-1 aggregation: 64 nodes/block, 4 lanes/node, uint2 (8B) gathers,
// 8-deep unroll (8 independent loads in flight). Register accumulation,
// fused bias+ReLU -> packed bf16 H1.
// ---------------------------------------------------------------------------
__global__ __launch_bounds__(256) void k_agg1(const int* __restrict__ node_off,
                                              const unsigned* __restrict__ csr,
                                              const uint2* __restrict__ Yu2,
                                              const float* __restrict__ bias1,
                                              uint2* __restrict__ H1u2) {
    int tid = threadIdx.x;
    int g = tid >> 2, c = tid & 3;
    int n = blockIdx.x * 64 + g;
    if (n >= N_NODES) return;
    int idx = n + (n >> 8);
    int beg = node_off[idx], end = node_off[idx + 1];

    float a[4] = {0.f, 0.f, 0.f, 0.f}, b[4] = {0.f, 0.f, 0.f, 0.f};
    int i = beg;
    for (; i + 7 < end; i += 8) {
        unsigned s0 = csr[i],     s1 = csr[i + 1], s2 = csr[i + 2], s3 = csr[i + 3];
        unsigned s4 = csr[i + 4], s5 = csr[i + 5], s6 = csr[i + 6], s7 = csr[i + 7];
        uint2 w0 = Yu2[(size_t)s0 * 4 + c];
        uint2 w1 = Yu2[(size_t)s1 * 4 + c];
        uint2 w2 = Yu2[(size_t)s2 * 4 + c];
        uint2 w3 = Yu2[(size_t)s3 * 4 + c];
        uint2 w4 = Yu2[(size_t)s4 * 4 + c];
        uint2 w5 = Yu2[(size_t)s5 * 4 + c];
        uint2 w6 = Yu2[(size_t)s6 * 4 + c];
        uint2 w7 = Yu2[(size_t)s7 * 4 + c];
        acc4(a, w0); acc4(b, w1); acc4(a, w2); acc4(b, w3);
        acc4(a, w4); acc4(b, w5); acc4(a, w6); acc4(b, w7);
    }
    for (; i < end; ++i) {
        uint2 w = Yu2[(size_t)csr[i] * 4 + c];
        acc4(a, w);
    }
    float f0 = a[0] + b[0] + bias1[c * 4 + 0];
    float f1 = a[1] + b[1] + bias1[c * 4 + 1];
    float f2 = a[2] + b[2] + bias1[c * 4 + 2];
    float f3 = a[3] + b[3] + bias1[c * 4 + 3];
    uint2 o;
    o.x = bf_pack(fmaxf(f0, 0.f), fmaxf(f1, 0.f));
    o.y = bf_pack(fmaxf(f2, 0.f), fmaxf(f3, 0.f));
    H1u2[(size_t)n * 4 + c] = o;
}

// ---------------------------------------------------------------------------
// K5: layer-2 aggregation (same gather structure) + fused mm2 epilogue.
// ---------------------------------------------------------------------------
__global__ __launch_bounds__(256) void k_agg2(const int* __restrict__ node_off,
                                              const unsigned* __restrict__ csr,
                                              const uint2* __restrict__ H1u2,
                                              const float* __restrict__ W2,
                                              const float* __restrict__ b2,
                                              float* __restrict__ out) {
    __shared__ float sacc[64][D_HID + 1];  // 4.4 KB
    __shared__ float sW2[D_HID * D_OUT];   // 2 KB
    __shared__ float sb2[D_OUT];
    int tid = threadIdx.x;
    for (int i2 = tid; i2 < D_HID * D_OUT; i2 += 256) sW2[i2] = W2[i2];
    if (tid < D_OUT) sb2[tid] = b2[tid];

    int g = tid >> 2, c = tid & 3;
    int n = blockIdx.x * 64 + g;

    float a[4] = {0.f, 0.f, 0.f, 0.f}, b[4] = {0.f, 0.f, 0.f, 0.f};
    if (n < N_NODES) {
        int idx = n + (n >> 8);
        int beg = node_off[idx], end = node_off[idx + 1];
        int i = beg;
        for (; i + 7 < end; i += 8) {
            unsigned s0 = csr[i],     s1 = csr[i + 1], s2 = csr[i + 2], s3 = csr[i + 3];
            unsigned s4 = csr[i + 4], s5 = csr[i + 5], s6 = csr[i + 6], s7 = csr[i + 7];
            uint2 w0 = H1u2[(size_t)s0 * 4 + c];
            uint2 w1 = H1u2[(size_t)s1 * 4 + c];
            uint2 w2 = H1u2[(size_t)s2 * 4 + c];
            uint2 w3 = H1u2[(size_t)s3 * 4 + c];
            uint2 w4 = H1u2[(size_t)s4 * 4 + c];
            uint2 w5 = H1u2[(size_t)s5 * 4 + c];
            uint2 w6 = H1u2[(size_t)s6 * 4 + c];
            uint2 w7 = H1u2[(size_t)s7 * 4 + c];
            acc4(a, w0); acc4(b, w1); acc4(a, w2); acc4(b, w3);
            acc4(a, w4); acc4(b, w5); acc4(a, w6); acc4(b, w7);
        }
        for (; i < end; ++i) {
            uint2 w = H1u2[(size_t)csr[i] * 4 + c];
            acc4(a, w);
        }
    }
    sacc[g][c * 4 + 0] = a[0] + b[0];
    sacc[g][c * 4 + 1] = a[1] + b[1];
    sacc[g][c * 4 + 2] = a[2] + b[2];
    sacc[g][c * 4 + 3] = a[3] + b[3];
    __syncthreads();

    // mm2: 64 nodes x 32 outputs = 2048 -> 8 per thread
    for (int t2 = tid; t2 < 64 * D_OUT; t2 += 256) {
        int gg = t2 >> 5, o = t2 & 31;
        int node = blockIdx.x * 64 + gg;
        if (node < N_NODES) {
            float acc = sb2[o];
#pragma unroll
            for (int j = 0; j < D_HID; ++j)
                acc = fmaf(sacc[gg][j], sW2[j * D_OUT + o], acc);
            out[(size_t)node * D_OUT + o] = acc;
        }
    }
}

// ---------------------------------------------------------------------------
extern "C" void kernel_launch(void* const* d_in, const int* in_sizes, int n_in,
                              void* d_out, int out_size, void* d_ws, size_t ws_size,
                              hipStream_t stream) {
    const float* feat = (const float*)d_in[0];
    const int*   src  = (const int*)d_in[1];
    const int*   dst  = (const int*)d_in[2];
    const float* W1   = (const float*)d_in[3];
    const float* b1   = (const float*)d_in[4];
    const float* W2   = (const float*)d_in[5];
    const float* b2   = (const float*)d_in[6];
    float* out = (float*)d_out;

    // ws layout (~14.0 MB):
    //   [0        , 7206912 )  pairs/csr slabs (NB * SLAB u32)
    //   [7208960  , +3.2M   )  Yu   (bf16x16 rows, packed)
    //   [10408960 , +3.2M   )  H1u  (bf16x16 rows, packed)
    //   [13608960 , +1.6K   )  cursor   (NB ints, slab-based)
    //   [13613056 , +402K   )  node_off (NB*257 ints)
    char* base = (char*)d_ws;
    unsigned* pairs    = (unsigned*)(base);
    unsigned* Yu       = (unsigned*)(base + 7208960);
    unsigned* H1u      = (unsigned*)(base + 10408960);
    int*      cursor   = (int*)(base + 13608960);
    int*      node_off = (int*)(base + 13613056);

    // K1: projection (4 thr/node) + slab cursor init
    k_mm1        <<<(N_NODES * 4 + 255) / 256, 256, 0, stream>>>(feat, W1, Yu, cursor);
    // K2: bucket-grouping counting sort into slabs (no hist/scan kernels)
    k_sortscatter<<<SBLOCKS, 256, 0, stream>>>(src, dst, cursor, pairs);
    // K3: per-bucket node sort -> csr + node_off
    k_nodesort   <<<NB, 256, 0, stream>>>(cursor, pairs, node_off);
    // K4: layer-1 aggregation (fused bias+ReLU)
    k_agg1       <<<(N_NODES + 63) / 64, 256, 0, stream>>>(node_off, pairs,
                                                           (const uint2*)Yu, b1,
                                                           (uint2*)H1u);
    // K5: layer-2 aggregation + fused mm2
    k_agg2       <<<(N_NODES + 63) / 64, 256, 0, stream>>>(node_off, pairs,
                                                           (const uint2*)H1u, W2, b2, out);
}